// Round 13
// baseline (54.093 us; speedup 1.0000x reference)
//
#include <hip/hip_runtime.h>
#include <hip/hip_bf16.h>
#include <stdint.h>

#define HID 768

typedef short bf16x8 __attribute__((ext_vector_type(8)));
typedef unsigned short ushort8_t __attribute__((ext_vector_type(8)));
typedef float f32x4 __attribute__((ext_vector_type(4)));

// packed f32x2 -> bf16x2 (compiler emits v_cvt_pk_bf16_f32)
__device__ __forceinline__ unsigned int pack2bf(float x, float y) {
    __hip_bfloat162 h = __float22bfloat162_rn(make_float2(x, y));
    return *reinterpret_cast<unsigned int*>(&h);
}
__device__ __forceinline__ unsigned short f2bf1(float x) {
    __hip_bfloat16 h = __float2bfloat16(x);
    return *reinterpret_cast<unsigned short*>(&h);
}

// async global->LDS, 16B per lane; lds dest = wave-uniform base + lane*16
__device__ __forceinline__ void gload_lds16(const void* g, void* l) {
    __builtin_amdgcn_global_load_lds(
        (const __attribute__((address_space(1))) unsigned int*)g,
        (__attribute__((address_space(3))) unsigned int*)l, 16, 0, 0);
}

// ---------------- combo: blocks 0..95 = AB gemm (W1 consumed untransposed);
//                  blocks 96..431 = W2/W3 transpose+cast. Plain barriers only.
__launch_bounds__(256, 2)
__global__ void prep_ab_k(const float* __restrict__ F,     // feat [256][768]
                          const float* __restrict__ W1,    // [1536][768] f32
                          const float* __restrict__ b1,    // [768]
                          const float* __restrict__ W2,    // [768][384]
                          const float* __restrict__ W3,    // [384][128]
                          unsigned short* __restrict__ W2t,
                          unsigned short* __restrict__ W3t,
                          float* __restrict__ AB) {        // [256][1536]
    __shared__ alignas(1024) char smem[51200];
    int b = blockIdx.x;

    if (b >= 96) {
        float (*t)[33] = (float(*)[33])smem;
        int b2 = b - 96;
        const float* in; unsigned short* op; int R, C, bx, by;
        if (b2 < 288) { in = W2; op = W2t; R = 768; C = 384; bx = b2 % 12; by = b2 / 12; }
        else          { int b3i = b2 - 288; in = W3; op = W3t; R = 384; C = 128; bx = b3i % 4; by = b3i / 4; }
        int c0 = bx * 32, r0 = by * 32;
        int tx = threadIdx.x & 31, ty = threadIdx.x >> 5;   // 32 x 8
        #pragma unroll
        for (int k = 0; k < 4; ++k)
            t[ty + 8*k][tx] = in[(size_t)(r0 + ty + 8*k) * C + c0 + tx];
        __syncthreads();
        #pragma unroll
        for (int k = 0; k < 4; ++k)
            op[(size_t)(c0 + ty + 8*k) * R + r0 + tx] = f2bf1(t[tx][ty + 8*k]);
        return;
    }

    unsigned short* fl = (unsigned short*)smem;             // 2 x [64][72] bf16
    float*          wt = (float*)(smem + 18432);            // 2 x [64][64] f32

    int tid = threadIdx.x;
    int lane = tid & 63, wid = tid >> 6;   // 4 waves
    int bx = b % 24, by = b / 24;
    int n0 = bx * 64, m0 = by * 64;
    const float* Wsrc = W1 + (n0 < 768 ? 0 : (size_t)768*768);
    int cb = (n0 < 768) ? n0 : n0 - 768;

    f32x4 acc[4] = {};
    float4 rf[2][2];

    #pragma unroll
    for (int s = 0; s < 4; ++s) {
        int chunk = wid*4 + s;
        int rk = chunk*4 + (lane>>4);
        int c16 = (lane&15)*4;
        gload_lds16(Wsrc + (size_t)rk*HID + cb + c16, (char*)wt + chunk*1024);
    }
    #pragma unroll
    for (int s = 0; s < 2; ++s) {
        int idx = tid + s*256;
        int r = idx >> 3, c8 = idx & 7;
        const float4* src = (const float4*)(F + (size_t)(m0 + r)*HID + c8*8);
        rf[s][0] = src[0]; rf[s][1] = src[1];
    }
    #pragma unroll
    for (int s = 0; s < 2; ++s) {
        int idx = tid + s*256;
        int r = idx >> 3, c8 = idx & 7;
        unsigned int us32[4] = { pack2bf(rf[s][0].x, rf[s][0].y), pack2bf(rf[s][0].z, rf[s][0].w),
                                 pack2bf(rf[s][1].x, rf[s][1].y), pack2bf(rf[s][1].z, rf[s][1].w) };
        *(ushort8_t*)(fl + r*72 + c8*8) = *(ushort8_t*)us32;
    }
    __syncthreads();

    for (int t = 0; t < 12; ++t) {
        int cur = t & 1;
        unsigned short* flc = fl + cur*(64*72);
        float* wtc = wt + cur*(64*64);
        if (t < 11) {
            int kk = (t+1) * 64;
            float* wtn = wt + (cur^1)*(64*64);
            #pragma unroll
            for (int s = 0; s < 4; ++s) {
                int chunk = wid*4 + s;
                int rk = chunk*4 + (lane>>4);
                int c16 = (lane&15)*4;
                gload_lds16(Wsrc + (size_t)(kk + rk)*HID + cb + c16, (char*)wtn + chunk*1024);
            }
            #pragma unroll
            for (int s = 0; s < 2; ++s) {
                int idx = tid + s*256;
                int r = idx >> 3, c8 = idx & 7;
                const float4* src = (const float4*)(F + (size_t)(m0 + r)*HID + kk + c8*8);
                rf[s][0] = src[0]; rf[s][1] = src[1];
            }
        }
        __builtin_amdgcn_s_setprio(1);
        #pragma unroll
        for (int ks = 0; ks < 2; ++ks) {
            bf16x8 a[4], bfrag;
            #pragma unroll
            for (int fm = 0; fm < 4; ++fm)
                a[fm] = *(const bf16x8*)(flc + (fm*16 + (lane&15))*72 + ks*32 + (lane>>4)*8);
            {
                int nl = wid*16 + (lane&15);
                int k0 = ks*32 + (lane>>4)*8;
                float v[8];
                #pragma unroll
                for (int d = 0; d < 8; ++d)
                    v[d] = wtc[(k0 + d)*64 + nl];
                unsigned int us[4] = { pack2bf(v[0],v[1]), pack2bf(v[2],v[3]),
                                       pack2bf(v[4],v[5]), pack2bf(v[6],v[7]) };
                bfrag = *(bf16x8*)us;
            }
            #pragma unroll
            for (int fm = 0; fm < 4; ++fm)
                acc[fm] = __builtin_amdgcn_mfma_f32_16x16x32_bf16(a[fm], bfrag, acc[fm], 0,0,0);
        }
        __builtin_amdgcn_s_setprio(0);
        if (t < 11) {
            unsigned short* fln = fl + (cur^1)*(64*72);
            #pragma unroll
            for (int s = 0; s < 2; ++s) {
                int idx = tid + s*256;
                int r = idx >> 3, c8 = idx & 7;
                unsigned int us32[4] = { pack2bf(rf[s][0].x, rf[s][0].y), pack2bf(rf[s][0].z, rf[s][0].w),
                                         pack2bf(rf[s][1].x, rf[s][1].y), pack2bf(rf[s][1].z, rf[s][1].w) };
                *(ushort8_t*)(fln + r*72 + c8*8) = *(ushort8_t*)us32;
            }
        }
        __syncthreads();
    }
    #pragma unroll
    for (int fm = 0; fm < 4; ++fm)
        #pragma unroll
        for (int q = 0; q < 4; ++q) {
            int row = m0 + fm*16 + (lane>>4)*4 + q;
            int col = n0 + wid*16 + (lane&15);
            float bias = (col < 768) ? b1[col] : 0.0f;
            AB[(size_t)row*1536 + col] = acc[fm][q] + bias;
        }
}

// ---------------- fused pair MLP: 512 thr / 8 waves, wave tile 128x48 -----------
// acc2[8][3] (96 AGPR) -> 22 ds_read_b128 per 48 MFMA (-21% LDS reads/FLOP vs r12).
// dbuf h1 + dbuf w2 (gload_lds, swizzled); plain __syncthreads only.
__launch_bounds__(512, 2)
__global__ void fused_k(const float* __restrict__ AB,            // [256][1536] f32
                        const unsigned short* __restrict__ W2t,  // [384][768] bf16
                        const float* __restrict__ b2,            // [384]
                        const unsigned short* __restrict__ W3t,  // [128][384] bf16
                        const float* __restrict__ b3,            // [128]
                        float* __restrict__ out) {               // [32640][128] f32
    __shared__ alignas(1024) char smem[135168];
    unsigned short* h1b = (unsigned short*)(smem);            // 2 x [128][72]   (36,864 B)
    unsigned short* w2b = (unsigned short*)(smem + 36864);    // 2 x [384][64] swizzled (98,304 B)
    unsigned short* h2  = (unsigned short*)(smem);            // [128][392] phase B (reuse)
    unsigned short* w3b = (unsigned short*)(smem + 100352);   // 2 x [128][64] swizzled (32,768 B)

    int tid = threadIdx.x;
    int lane = tid & 63, wid = tid >> 6;   // 8 waves
    int wc = wid;                          // phase A: 1 x 8 wave grid, tile 128 x 48
    int p0 = blockIdx.x * 128;

    // pair indices for my h1-gen row (4 threads per row, 16 cols each)
    int hr = tid >> 2;                     // 0..127
    int hc = (tid & 3) * 16;               // col chunk within 64
    int p = p0 + hr;
    float sdisc = sqrtf((float)(511*511 - 8*p));
    int i_me = (int)((511.0f - sdisc) * 0.5f);
    if (i_me < 0) i_me = 0; if (i_me > 254) i_me = 254;
    while (i_me < 255 && (i_me+1)*255 - (i_me+1)*i_me/2 <= p) ++i_me;
    while (i_me > 0 && i_me*255 - i_me*(i_me-1)/2 > p) --i_me;
    int j_me = i_me + 1 + (p - (i_me*255 - i_me*(i_me-1)/2));

    float4 ra[4], rb[4];

    // ---- prologue: h1(0) pack; w2(0) gloads; one barrier
    {
        const float4* pa = (const float4*)(AB + (size_t)i_me*1536 + hc);
        const float4* pb = (const float4*)(AB + (size_t)j_me*1536 + 768 + hc);
        #pragma unroll
        for (int u = 0; u < 4; ++u) { ra[u] = pa[u]; rb[u] = pb[u]; }
        unsigned int us32[8];
        #pragma unroll
        for (int u = 0; u < 4; ++u) {
            us32[u*2+0] = pack2bf(fmaxf(ra[u].x + rb[u].x, 0.f), fmaxf(ra[u].y + rb[u].y, 0.f));
            us32[u*2+1] = pack2bf(fmaxf(ra[u].z + rb[u].z, 0.f), fmaxf(ra[u].w + rb[u].w, 0.f));
        }
        *(ushort8_t*)(h1b + hr*72 + hc)     = *(ushort8_t*)(us32);
        *(ushort8_t*)(h1b + hr*72 + hc + 8) = *(ushort8_t*)(us32 + 4);
    }
    #pragma unroll
    for (int s = 0; s < 6; ++s) {
        int chunk = wid*6 + s;                 // 48 chunks of 1024B
        int row = chunk*8 + (lane>>3);
        int cg = (lane&7) ^ (row&7);
        gload_lds16(W2t + (size_t)row*HID + cg*8, (char*)w2b + chunk*1024);
    }
    __syncthreads();

    f32x4 acc2[8][3] = {};
    for (int t = 0; t < 12; ++t) {
        int cur = t & 1;
        unsigned short* h1c = h1b + cur * (128*72);
        unsigned short* w2c = w2b + cur * (384*64);
        if (t < 11) {                          // issue next-step loads BEFORE compute
            int kk = (t+1) * 64;
            unsigned short* w2n = w2b + (cur^1) * (384*64);
            #pragma unroll
            for (int s = 0; s < 6; ++s) {
                int chunk = wid*6 + s;
                int row = chunk*8 + (lane>>3);
                int cg = (lane&7) ^ (row&7);
                gload_lds16(W2t + (size_t)row*HID + kk + cg*8, (char*)w2n + chunk*1024);
            }
            const float4* pa = (const float4*)(AB + (size_t)i_me*1536 + kk + hc);
            const float4* pb = (const float4*)(AB + (size_t)j_me*1536 + 768 + kk + hc);
            #pragma unroll
            for (int u = 0; u < 4; ++u) { ra[u] = pa[u]; rb[u] = pb[u]; }
        }
        __builtin_amdgcn_s_setprio(1);
        #pragma unroll
        for (int ks = 0; ks < 2; ++ks) {
            bf16x8 bfr[3];
            #pragma unroll
            for (int fn = 0; fn < 3; ++fn) {
                int n = wc*48 + fn*16 + (lane&15);
                int g = ks*4 + (lane>>4);
                bfr[fn] = *(const bf16x8*)(w2c + n*64 + ((g ^ (n&7)) * 8));
            }
            #pragma unroll
            for (int fm = 0; fm < 8; ++fm) {
                bf16x8 a = *(const bf16x8*)(h1c + (fm*16 + (lane&15))*72 + ks*32 + (lane>>4)*8);
                #pragma unroll
                for (int fn = 0; fn < 3; ++fn)
                    acc2[fm][fn] = __builtin_amdgcn_mfma_f32_16x16x32_bf16(a, bfr[fn], acc2[fm][fn], 0,0,0);
            }
        }
        __builtin_amdgcn_s_setprio(0);
        if (t < 11) {                          // pack prefetched AB -> h1[next]
            unsigned short* h1n = h1b + (cur^1) * (128*72);
            unsigned int us32[8];
            #pragma unroll
            for (int u = 0; u < 4; ++u) {
                us32[u*2+0] = pack2bf(fmaxf(ra[u].x + rb[u].x, 0.f), fmaxf(ra[u].y + rb[u].y, 0.f));
                us32[u*2+1] = pack2bf(fmaxf(ra[u].z + rb[u].z, 0.f), fmaxf(ra[u].w + rb[u].w, 0.f));
            }
            *(ushort8_t*)(h1n + hr*72 + hc)     = *(ushort8_t*)(us32);
            *(ushort8_t*)(h1n + hr*72 + hc + 8) = *(ushort8_t*)(us32 + 4);
        }
        __syncthreads();
    }

    // ---- phase transition: h2 = relu(acc2 + b2) -> [128][392]; stage w3(0)
    #pragma unroll
    for (int fn = 0; fn < 3; ++fn) {
        int col = wc*48 + fn*16 + (lane&15);
        float bb = b2[col];
        #pragma unroll
        for (int fm = 0; fm < 8; ++fm)
            #pragma unroll
            for (int q = 0; q < 4; ++q) {
                int row = fm*16 + (lane>>4)*4 + q;
                h2[row*392 + col] = f2bf1(fmaxf(acc2[fm][fn][q] + bb, 0.f));
            }
    }
    #pragma unroll
    for (int s = 0; s < 2; ++s) {              // w3(0): 16 chunks, 2 per wave
        int chunk = wid*2 + s;
        int row = chunk*8 + (lane>>3);
        int cg = (lane&7) ^ (row&7);
        gload_lds16(W3t + (size_t)row*384 + cg*8, (char*)w3b + chunk*1024);
    }
    __syncthreads();

    // ---- phase B: 2x4 wave grid, tile 64x32, dbuf w3
    int wrB = wid >> 2, wcB = wid & 3;
    f32x4 acc3[4][2] = {};
    for (int kt = 0; kt < 6; ++kt) {
        int cur = kt & 1;
        unsigned short* w3c = w3b + cur * (128*64);
        if (kt < 5) {
            unsigned short* w3n = w3b + (cur^1) * (128*64);
            #pragma unroll
            for (int s = 0; s < 2; ++s) {
                int chunk = wid*2 + s;
                int row = chunk*8 + (lane>>3);
                int cg = (lane&7) ^ (row&7);
                gload_lds16(W3t + (size_t)row*384 + (kt+1)*64 + cg*8, (char*)w3n + chunk*1024);
            }
        }
        __builtin_amdgcn_s_setprio(1);
        #pragma unroll
        for (int ks = 0; ks < 2; ++ks) {
            bf16x8 bfr[2];
            #pragma unroll
            for (int fn = 0; fn < 2; ++fn) {
                int n = wcB*32 + fn*16 + (lane&15);
                int g = ks*4 + (lane>>4);
                bfr[fn] = *(const bf16x8*)(w3c + n*64 + ((g ^ (n&7)) * 8));
            }
            #pragma unroll
            for (int fm = 0; fm < 4; ++fm) {
                bf16x8 a = *(const bf16x8*)(h2 + (wrB*64 + fm*16 + (lane&15))*392 + kt*64 + ks*32 + (lane>>4)*8);
                #pragma unroll
                for (int fn = 0; fn < 2; ++fn)
                    acc3[fm][fn] = __builtin_amdgcn_mfma_f32_16x16x32_bf16(a, bfr[fn], acc3[fm][fn], 0,0,0);
            }
        }
        __builtin_amdgcn_s_setprio(0);
        __syncthreads();
    }
    #pragma unroll
    for (int fm = 0; fm < 4; ++fm)
        #pragma unroll
        for (int fn = 0; fn < 2; ++fn) {
            int col = wcB*32 + fn*16 + (lane&15);
            float bb = b3[col];
            #pragma unroll
            for (int q = 0; q < 4; ++q) {
                int row = p0 + wrB*64 + fm*16 + (lane>>4)*4 + q;
                out[(size_t)row*128 + col] = acc3[fm][fn][q] + bb;
            }
        }
}

extern "C" void kernel_launch(void* const* d_in, const int* in_sizes, int n_in,
                              void* d_out, int out_size, void* d_ws, size_t ws_size,
                              hipStream_t stream) {
    const float* feat = (const float*)d_in[0];  // [256][768]
    const float* W1   = (const float*)d_in[1];  // [1536][768]
    const float* b1   = (const float*)d_in[2];  // [768]
    const float* W2   = (const float*)d_in[3];  // [768][384]
    const float* b2   = (const float*)d_in[4];  // [384]
    const float* W3   = (const float*)d_in[5];  // [384][128]
    const float* b3   = (const float*)d_in[6];  // [128]
    float* out = (float*)d_out;

    char* ws = (char*)d_ws;
    unsigned short* W2t = (unsigned short*)(ws + 0);        // 384*768*2 = 589,824
    unsigned short* W3t = (unsigned short*)(ws + 589824);   // 128*384*2 =  98,304
    float*          AB  = (float*)        (ws + 688128);    // 256*1536*4 = 1,572,864

    prep_ab_k<<<432, 256, 0, stream>>>(feat, W1, b1, W2, W3, W2t, W3t, AB);
    fused_k<<<255, 512, 0, stream>>>(AB, W2t, b2, W3t, b3, out);
}

// Round 14
// 48.498 us; speedup vs baseline: 1.1154x; 1.1154x over previous
//
#include <hip/hip_runtime.h>
#include <hip/hip_bf16.h>
#include <stdint.h>

#define HID 768

typedef short bf16x8 __attribute__((ext_vector_type(8)));
typedef unsigned short ushort8_t __attribute__((ext_vector_type(8)));
typedef float f32x4 __attribute__((ext_vector_type(4)));

// packed f32x2 -> bf16x2 (compiler emits v_cvt_pk_bf16_f32)
__device__ __forceinline__ unsigned int pack2bf(float x, float y) {
    __hip_bfloat162 h = __float22bfloat162_rn(make_float2(x, y));
    return *reinterpret_cast<unsigned int*>(&h);
}
__device__ __forceinline__ unsigned short f2bf1(float x) {
    __hip_bfloat16 h = __float2bfloat16(x);
    return *reinterpret_cast<unsigned short*>(&h);
}

// async global->LDS, 16B per lane; lds dest = wave-uniform base + lane*16
__device__ __forceinline__ void gload_lds16(const void* g, void* l) {
    __builtin_amdgcn_global_load_lds(
        (const __attribute__((address_space(1))) unsigned int*)g,
        (__attribute__((address_space(3))) unsigned int*)l, 16, 0, 0);
}

// ---------------- combo: blocks 0..95 = AB gemm (W1 consumed untransposed);
//                  blocks 96..431 = W2/W3 transpose+cast.
// Sync: ONLY __syncthreads() (drains vmcnt+lgkmcnt) — no hand-counted waits.
__launch_bounds__(256, 2)
__global__ void prep_ab_k(const float* __restrict__ F,     // feat [256][768]
                          const float* __restrict__ W1,    // [1536][768] f32
                          const float* __restrict__ b1,    // [768]
                          const float* __restrict__ W2,    // [768][384]
                          const float* __restrict__ W3,    // [384][128]
                          unsigned short* __restrict__ W2t,
                          unsigned short* __restrict__ W3t,
                          float* __restrict__ AB) {        // [256][1536]
    __shared__ alignas(1024) char smem[51200];
    int b = blockIdx.x;

    if (b >= 96) {
        // ---- transpose path: f32 [R][C] -> bf16 [C][R]
        float (*t)[33] = (float(*)[33])smem;
        int b2 = b - 96;
        const float* in; unsigned short* op; int R, C, bx, by;
        if (b2 < 288) { in = W2; op = W2t; R = 768; C = 384; bx = b2 % 12; by = b2 / 12; }
        else          { int b3i = b2 - 288; in = W3; op = W3t; R = 384; C = 128; bx = b3i % 4; by = b3i / 4; }
        int c0 = bx * 32, r0 = by * 32;
        int tx = threadIdx.x & 31, ty = threadIdx.x >> 5;   // 32 x 8
        #pragma unroll
        for (int k = 0; k < 4; ++k)
            t[ty + 8*k][tx] = in[(size_t)(r0 + ty + 8*k) * C + c0 + tx];
        __syncthreads();
        #pragma unroll
        for (int k = 0; k < 4; ++k)
            op[(size_t)(c0 + ty + 8*k) * R + r0 + tx] = f2bf1(t[tx][ty + 8*k]);
        return;
    }

    // ---- gemm path: AB tile 64m x 64n, K=768
    unsigned short* fl = (unsigned short*)smem;             // 2 x [64][72] bf16 (18,432 B)
    float*          wt = (float*)(smem + 18432);            // 2 x [64][64] f32  (32,768 B)

    int tid = threadIdx.x;
    int lane = tid & 63, wid = tid >> 6;   // 4 waves
    int bx = b % 24, by = b / 24;
    int n0 = bx * 64, m0 = by * 64;
    const float* Wsrc = W1 + (n0 < 768 ? 0 : (size_t)768*768);
    int cb = (n0 < 768) ? n0 : n0 - 768;

    f32x4 acc[4] = {};
    float4 rf[2][2];

    // stage wt[0]: k-rows 0..63, cols cb..cb+63 (4 k-rows per 1KB chunk)
    #pragma unroll
    for (int s = 0; s < 4; ++s) {
        int chunk = wid*4 + s;                  // 16 chunks
        int rk = chunk*4 + (lane>>4);
        int c16 = (lane&15)*4;
        gload_lds16(Wsrc + (size_t)rk*HID + cb + c16, (char*)wt + chunk*1024);
    }
    #pragma unroll
    for (int s = 0; s < 2; ++s) {               // F tile 64x64 f32 -> regs
        int idx = tid + s*256;
        int r = idx >> 3, c8 = idx & 7;
        const float4* src = (const float4*)(F + (size_t)(m0 + r)*HID + c8*8);
        rf[s][0] = src[0]; rf[s][1] = src[1];
    }
    #pragma unroll
    for (int s = 0; s < 2; ++s) {
        int idx = tid + s*256;
        int r = idx >> 3, c8 = idx & 7;
        unsigned int us32[4] = { pack2bf(rf[s][0].x, rf[s][0].y), pack2bf(rf[s][0].z, rf[s][0].w),
                                 pack2bf(rf[s][1].x, rf[s][1].y), pack2bf(rf[s][1].z, rf[s][1].w) };
        *(ushort8_t*)(fl + r*72 + c8*8) = *(ushort8_t*)us32;
    }
    __syncthreads();

    for (int t = 0; t < 12; ++t) {
        int cur = t & 1;
        unsigned short* flc = fl + cur*(64*72);
        float* wtc = wt + cur*(64*64);
        if (t < 11) {
            int kk = (t+1) * 64;
            float* wtn = wt + (cur^1)*(64*64);
            #pragma unroll
            for (int s = 0; s < 4; ++s) {
                int chunk = wid*4 + s;
                int rk = chunk*4 + (lane>>4);
                int c16 = (lane&15)*4;
                gload_lds16(Wsrc + (size_t)(kk + rk)*HID + cb + c16, (char*)wtn + chunk*1024);
            }
            #pragma unroll
            for (int s = 0; s < 2; ++s) {
                int idx = tid + s*256;
                int r = idx >> 3, c8 = idx & 7;
                const float4* src = (const float4*)(F + (size_t)(m0 + r)*HID + kk + c8*8);
                rf[s][0] = src[0]; rf[s][1] = src[1];
            }
        }
        __builtin_amdgcn_s_setprio(1);
        #pragma unroll
        for (int ks = 0; ks < 2; ++ks) {
            bf16x8 a[4], bfrag;
            #pragma unroll
            for (int fm = 0; fm < 4; ++fm)
                a[fm] = *(const bf16x8*)(flc + (fm*16 + (lane&15))*72 + ks*32 + (lane>>4)*8);
            {   // b-frag: column gather from k-major f32 tile + pack to bf16
                int nl = wid*16 + (lane&15);
                int k0 = ks*32 + (lane>>4)*8;
                float v[8];
                #pragma unroll
                for (int d = 0; d < 8; ++d)
                    v[d] = wtc[(k0 + d)*64 + nl];
                unsigned int us[4] = { pack2bf(v[0],v[1]), pack2bf(v[2],v[3]),
                                       pack2bf(v[4],v[5]), pack2bf(v[6],v[7]) };
                bfrag = *(bf16x8*)us;
            }
            #pragma unroll
            for (int fm = 0; fm < 4; ++fm)
                acc[fm] = __builtin_amdgcn_mfma_f32_16x16x32_bf16(a[fm], bfrag, acc[fm], 0,0,0);
        }
        __builtin_amdgcn_s_setprio(0);
        if (t < 11) {
            unsigned short* fln = fl + (cur^1)*(64*72);
            #pragma unroll
            for (int s = 0; s < 2; ++s) {
                int idx = tid + s*256;
                int r = idx >> 3, c8 = idx & 7;
                unsigned int us32[4] = { pack2bf(rf[s][0].x, rf[s][0].y), pack2bf(rf[s][0].z, rf[s][0].w),
                                         pack2bf(rf[s][1].x, rf[s][1].y), pack2bf(rf[s][1].z, rf[s][1].w) };
                *(ushort8_t*)(fln + r*72 + c8*8) = *(ushort8_t*)us32;
            }
        }
        __syncthreads();
    }
    #pragma unroll
    for (int fm = 0; fm < 4; ++fm)
        #pragma unroll
        for (int q = 0; q < 4; ++q) {
            int row = m0 + fm*16 + (lane>>4)*4 + q;
            int col = n0 + wid*16 + (lane&15);
            float bias = (col < 768) ? b1[col] : 0.0f;   // fold b1 into A half
            AB[(size_t)row*1536 + col] = acc[fm][q] + bias;
        }
}

// ---------------- fused pair MLP: 16 waves, plain __syncthreads pipeline --------
// phase A: 2x8 wave grid (64x48 tiles), dbuf h1 + dbuf w2 (gload_lds, swizzled);
// phase B: 4x4 grid (32x32), dbuf w3. NO inline-asm waitcnt anywhere.
__launch_bounds__(1024, 1)
__global__ void fused_k(const float* __restrict__ AB,            // [256][1536] f32
                        const unsigned short* __restrict__ W2t,  // [384][768] bf16
                        const float* __restrict__ b2,            // [384]
                        const unsigned short* __restrict__ W3t,  // [128][384] bf16
                        const float* __restrict__ b3,            // [128]
                        float* __restrict__ out) {               // [32640][128] f32
    __shared__ alignas(1024) char smem[135168];
    unsigned short* h1b = (unsigned short*)(smem);            // 2 x [128][72]   (36,864 B)
    unsigned short* w2b = (unsigned short*)(smem + 36864);    // 2 x [384][64] swizzled (98,304 B)
    unsigned short* h2  = (unsigned short*)(smem);            // [128][392] phase B (reuse)
    unsigned short* w3b = (unsigned short*)(smem + 100352);   // 2 x [128][64] swizzled (32,768 B)

    int tid = threadIdx.x;
    int lane = tid & 63, wid = tid >> 6;   // 16 waves
    int wr = wid >> 3, wc = wid & 7;       // phase A: 2 x 8 wave grid
    int p0 = blockIdx.x * 128;

    int hr = tid >> 3;                     // 0..127
    int hc = (tid & 7) * 8;                // col chunk within 64
    int p = p0 + hr;
    float sdisc = sqrtf((float)(511*511 - 8*p));
    int i_me = (int)((511.0f - sdisc) * 0.5f);
    if (i_me < 0) i_me = 0; if (i_me > 254) i_me = 254;
    while (i_me < 255 && (i_me+1)*255 - (i_me+1)*i_me/2 <= p) ++i_me;
    while (i_me > 0 && i_me*255 - i_me*(i_me-1)/2 > p) --i_me;
    int j_me = i_me + 1 + (p - (i_me*255 - i_me*(i_me-1)/2));

    float4 ra[2], rb[2];

    // ---- prologue: h1(0) pack; w2(0) gloads; one barrier
    {
        const float4* pa = (const float4*)(AB + (size_t)i_me*1536 + hc);
        const float4* pb = (const float4*)(AB + (size_t)j_me*1536 + 768 + hc);
        ra[0] = pa[0]; ra[1] = pa[1]; rb[0] = pb[0]; rb[1] = pb[1];
        unsigned int us32[4];
        #pragma unroll
        for (int u = 0; u < 2; ++u) {
            us32[u*2+0] = pack2bf(fmaxf(ra[u].x + rb[u].x, 0.f), fmaxf(ra[u].y + rb[u].y, 0.f));
            us32[u*2+1] = pack2bf(fmaxf(ra[u].z + rb[u].z, 0.f), fmaxf(ra[u].w + rb[u].w, 0.f));
        }
        *(ushort8_t*)(h1b + hr*72 + hc) = *(ushort8_t*)us32;
    }
    #pragma unroll
    for (int s = 0; s < 3; ++s) {
        int chunk = wid*3 + s;                 // 48 chunks of 1024B
        int row = chunk*8 + (lane>>3);
        int cg = (lane&7) ^ (row&7);
        gload_lds16(W2t + (size_t)row*HID + cg*8, (char*)w2b + chunk*1024);
    }
    __syncthreads();

    f32x4 acc2[4][3] = {};
    for (int t = 0; t < 12; ++t) {
        int cur = t & 1;
        unsigned short* h1c = h1b + cur * (128*72);
        unsigned short* w2c = w2b + cur * (384*64);
        if (t < 11) {                          // issue next-step loads BEFORE compute
            int kk = (t+1) * 64;
            unsigned short* w2n = w2b + (cur^1) * (384*64);
            #pragma unroll
            for (int s = 0; s < 3; ++s) {
                int chunk = wid*3 + s;
                int row = chunk*8 + (lane>>3);
                int cg = (lane&7) ^ (row&7);
                gload_lds16(W2t + (size_t)row*HID + kk + cg*8, (char*)w2n + chunk*1024);
            }
            const float4* pa = (const float4*)(AB + (size_t)i_me*1536 + kk + hc);
            const float4* pb = (const float4*)(AB + (size_t)j_me*1536 + 768 + kk + hc);
            ra[0] = pa[0]; ra[1] = pa[1]; rb[0] = pb[0]; rb[1] = pb[1];
        }
        __builtin_amdgcn_s_setprio(1);
        #pragma unroll
        for (int ks = 0; ks < 2; ++ks) {
            bf16x8 a[4], bfr[3];
            #pragma unroll
            for (int fm = 0; fm < 4; ++fm)
                a[fm] = *(const bf16x8*)(h1c + (wr*64 + fm*16 + (lane&15))*72 + ks*32 + (lane>>4)*8);
            #pragma unroll
            for (int fn = 0; fn < 3; ++fn) {
                int n = wc*48 + fn*16 + (lane&15);
                int g = ks*4 + (lane>>4);
                bfr[fn] = *(const bf16x8*)(w2c + n*64 + ((g ^ (n&7)) * 8));
            }
            #pragma unroll
            for (int fm = 0; fm < 4; ++fm)
                #pragma unroll
                for (int fn = 0; fn < 3; ++fn)
                    acc2[fm][fn] = __builtin_amdgcn_mfma_f32_16x16x32_bf16(a[fm], bfr[fn], acc2[fm][fn], 0,0,0);
        }
        __builtin_amdgcn_s_setprio(0);
        if (t < 11) {                          // pack prefetched AB -> h1[next]
            unsigned short* h1n = h1b + (cur^1) * (128*72);
            unsigned int us32[4];
            #pragma unroll
            for (int u = 0; u < 2; ++u) {
                us32[u*2+0] = pack2bf(fmaxf(ra[u].x + rb[u].x, 0.f), fmaxf(ra[u].y + rb[u].y, 0.f));
                us32[u*2+1] = pack2bf(fmaxf(ra[u].z + rb[u].z, 0.f), fmaxf(ra[u].w + rb[u].w, 0.f));
            }
            *(ushort8_t*)(h1n + hr*72 + hc) = *(ushort8_t*)us32;
        }
        __syncthreads();
    }

    // ---- phase transition: h2 = relu(acc2 + b2) -> [128][392]; stage w3(0)
    #pragma unroll
    for (int fn = 0; fn < 3; ++fn) {
        int col = wc*48 + fn*16 + (lane&15);
        float bb = b2[col];
        #pragma unroll
        for (int fm = 0; fm < 4; ++fm)
            #pragma unroll
            for (int q = 0; q < 4; ++q) {
                int row = wr*64 + fm*16 + (lane>>4)*4 + q;
                h2[row*392 + col] = f2bf1(fmaxf(acc2[fm][fn][q] + bb, 0.f));
            }
    }
    {
        int chunk = wid;                       // 16 chunks, 1 per wave
        int row = chunk*8 + (lane>>3);
        int cg = (lane&7) ^ (row&7);
        gload_lds16(W3t + (size_t)row*384 + cg*8, (char*)w3b + chunk*1024);
    }
    __syncthreads();

    // ---- phase B: 4x4 wave grid, tile 32x32, dbuf w3
    int wrB = wid >> 2, wcB = wid & 3;
    f32x4 acc3[2][2] = {};
    for (int kt = 0; kt < 6; ++kt) {
        int cur = kt & 1;
        unsigned short* w3c = w3b + cur * (128*64);
        if (kt < 5) {
            unsigned short* w3n = w3b + (cur^1) * (128*64);
            int chunk = wid;
            int row = chunk*8 + (lane>>3);
            int cg = (lane&7) ^ (row&7);
            gload_lds16(W3t + (size_t)row*384 + (kt+1)*64 + cg*8, (char*)w3n + chunk*1024);
        }
        __builtin_amdgcn_s_setprio(1);
        #pragma unroll
        for (int ks = 0; ks < 2; ++ks) {
            bf16x8 a[2], bfr[2];
            #pragma unroll
            for (int fm = 0; fm < 2; ++fm)
                a[fm] = *(const bf16x8*)(h2 + (wrB*32 + fm*16 + (lane&15))*392 + kt*64 + ks*32 + (lane>>4)*8);
            #pragma unroll
            for (int fn = 0; fn < 2; ++fn) {
                int n = wcB*32 + fn*16 + (lane&15);
                int g = ks*4 + (lane>>4);
                bfr[fn] = *(const bf16x8*)(w3c + n*64 + ((g ^ (n&7)) * 8));
            }
            #pragma unroll
            for (int fm = 0; fm < 2; ++fm)
                #pragma unroll
                for (int fn = 0; fn < 2; ++fn)
                    acc3[fm][fn] = __builtin_amdgcn_mfma_f32_16x16x32_bf16(a[fm], bfr[fn], acc3[fm][fn], 0,0,0);
        }
        __builtin_amdgcn_s_setprio(0);
        __syncthreads();
    }
    #pragma unroll
    for (int fm = 0; fm < 2; ++fm)
        #pragma unroll
        for (int fn = 0; fn < 2; ++fn) {
            int col = wcB*32 + fn*16 + (lane&15);
            float bb = b3[col];
            #pragma unroll
            for (int q = 0; q < 4; ++q) {
                int row = p0 + wrB*32 + fm*16 + (lane>>4)*4 + q;
                out[(size_t)row*128 + col] = acc3[fm][fn][q] + bb;
            }
        }
}

extern "C" void kernel_launch(void* const* d_in, const int* in_sizes, int n_in,
                              void* d_out, int out_size, void* d_ws, size_t ws_size,
                              hipStream_t stream) {
    const float* feat = (const float*)d_in[0];  // [256][768]
    const float* W1   = (const float*)d_in[1];  // [1536][768]
    const float* b1   = (const float*)d_in[2];  // [768]
    const float* W2   = (const float*)d_in[3];  // [768][384]
    const float* b2   = (const float*)d_in[4];  // [384]
    const float* W3   = (const float*)d_in[5];  // [384][128]
    const float* b3   = (const float*)d_in[6];  // [128]
    float* out = (float*)d_out;

    char* ws = (char*)d_ws;
    unsigned short* W2t = (unsigned short*)(ws + 0);        // 384*768*2 = 589,824
    unsigned short* W3t = (unsigned short*)(ws + 589824);   // 128*384*2 =  98,304
    float*          AB  = (float*)        (ws + 688128);    // 256*1536*4 = 1,572,864

    prep_ab_k<<<432, 256, 0, stream>>>(feat, W1, b1, W2, W3, W2t, W3t, AB);
    fused_k<<<255, 1024, 0, stream>>>(AB, W2t, b2, W3t, b3, out);
}

// Round 15
// 47.279 us; speedup vs baseline: 1.1441x; 1.0258x over previous
//
#include <hip/hip_runtime.h>
#include <hip/hip_bf16.h>
#include <stdint.h>

#define HID 768

typedef short bf16x8 __attribute__((ext_vector_type(8)));
typedef unsigned short ushort8_t __attribute__((ext_vector_type(8)));
typedef float f32x4 __attribute__((ext_vector_type(4)));

// packed f32x2 -> bf16x2 (compiler emits v_cvt_pk_bf16_f32)
__device__ __forceinline__ unsigned int pack2bf(float x, float y) {
    __hip_bfloat162 h = __float22bfloat162_rn(make_float2(x, y));
    return *reinterpret_cast<unsigned int*>(&h);
}
__device__ __forceinline__ unsigned short f2bf1(float x) {
    __hip_bfloat16 h = __float2bfloat16(x);
    return *reinterpret_cast<unsigned short*>(&h);
}

// async global->LDS, 16B per lane; lds dest = wave-uniform base + lane*16
__device__ __forceinline__ void gload_lds16(const void* g, void* l) {
    __builtin_amdgcn_global_load_lds(
        (const __attribute__((address_space(1))) unsigned int*)g,
        (__attribute__((address_space(3))) unsigned int*)l, 16, 0, 0);
}

// ---------------- combo: blocks 0..95 = AB gemm (W1 consumed untransposed,
//                  K-step 128 -> 6 barriered steps); blocks 96..431 = W2/W3
//                  transpose+cast. Sync: ONLY __syncthreads().
__launch_bounds__(256, 2)
__global__ void prep_ab_k(const float* __restrict__ F,     // feat [256][768]
                          const float* __restrict__ W1,    // [1536][768] f32
                          const float* __restrict__ b1,    // [768]
                          const float* __restrict__ W2,    // [768][384]
                          const float* __restrict__ W3,    // [384][128]
                          unsigned short* __restrict__ W2t,
                          unsigned short* __restrict__ W3t,
                          float* __restrict__ AB) {        // [256][1536]
    __shared__ alignas(1024) char smem[102400];
    int b = blockIdx.x;

    if (b >= 96) {
        // ---- transpose path: f32 [R][C] -> bf16 [C][R]
        float (*t)[33] = (float(*)[33])smem;
        int b2 = b - 96;
        const float* in; unsigned short* op; int R, C, bx, by;
        if (b2 < 288) { in = W2; op = W2t; R = 768; C = 384; bx = b2 % 12; by = b2 / 12; }
        else          { int b3i = b2 - 288; in = W3; op = W3t; R = 384; C = 128; bx = b3i % 4; by = b3i / 4; }
        int c0 = bx * 32, r0 = by * 32;
        int tx = threadIdx.x & 31, ty = threadIdx.x >> 5;   // 32 x 8
        #pragma unroll
        for (int k = 0; k < 4; ++k)
            t[ty + 8*k][tx] = in[(size_t)(r0 + ty + 8*k) * C + c0 + tx];
        __syncthreads();
        #pragma unroll
        for (int k = 0; k < 4; ++k)
            op[(size_t)(c0 + ty + 8*k) * R + r0 + tx] = f2bf1(t[tx][ty + 8*k]);
        return;
    }

    // ---- gemm path: AB tile 64m x 64n, K=768 in 6 steps of 128
    unsigned short* fl = (unsigned short*)smem;             // 2 x [64][136] bf16 (34,816 B)
    float*          wt = (float*)(smem + 34816);            // 2 x [128][64] f32  (65,536 B)

    int tid = threadIdx.x;
    int lane = tid & 63, wid = tid >> 6;   // 4 waves
    int bx = b % 24, by = b / 24;
    int n0 = bx * 64, m0 = by * 64;
    const float* Wsrc = W1 + (n0 < 768 ? 0 : (size_t)768*768);
    int cb = (n0 < 768) ? n0 : n0 - 768;

    f32x4 acc[4] = {};
    float4 rf[4][2];

    // stage wt[0]: k-rows 0..127, cols cb..cb+63 (4 k-rows per 1KB chunk, 32 chunks)
    #pragma unroll
    for (int s = 0; s < 8; ++s) {
        int chunk = wid*8 + s;
        int rk = chunk*4 + (lane>>4);
        int c16 = (lane&15)*4;
        gload_lds16(Wsrc + (size_t)rk*HID + cb + c16, (char*)wt + chunk*1024);
    }
    // F tile [64 m][128 k] f32 -> regs -> bf16 LDS (4 groups of 8 elems per thread)
    #pragma unroll
    for (int s = 0; s < 4; ++s) {
        int idx = tid + s*256;
        int r = idx >> 4, c8 = idx & 15;
        const float4* src = (const float4*)(F + (size_t)(m0 + r)*HID + c8*8);
        rf[s][0] = src[0]; rf[s][1] = src[1];
    }
    #pragma unroll
    for (int s = 0; s < 4; ++s) {
        int idx = tid + s*256;
        int r = idx >> 4, c8 = idx & 15;
        unsigned int us32[4] = { pack2bf(rf[s][0].x, rf[s][0].y), pack2bf(rf[s][0].z, rf[s][0].w),
                                 pack2bf(rf[s][1].x, rf[s][1].y), pack2bf(rf[s][1].z, rf[s][1].w) };
        *(ushort8_t*)(fl + r*136 + c8*8) = *(ushort8_t*)us32;
    }
    __syncthreads();

    for (int t = 0; t < 6; ++t) {
        int cur = t & 1;
        unsigned short* flc = fl + cur*(64*136);
        float* wtc = wt + cur*(128*64);
        if (t < 5) {
            int kk = (t+1) * 128;
            float* wtn = wt + (cur^1)*(128*64);
            #pragma unroll
            for (int s = 0; s < 8; ++s) {
                int chunk = wid*8 + s;
                int rk = chunk*4 + (lane>>4);
                int c16 = (lane&15)*4;
                gload_lds16(Wsrc + (size_t)(kk + rk)*HID + cb + c16, (char*)wtn + chunk*1024);
            }
            #pragma unroll
            for (int s = 0; s < 4; ++s) {
                int idx = tid + s*256;
                int r = idx >> 4, c8 = idx & 15;
                const float4* src = (const float4*)(F + (size_t)(m0 + r)*HID + kk + c8*8);
                rf[s][0] = src[0]; rf[s][1] = src[1];
            }
        }
        __builtin_amdgcn_s_setprio(1);
        #pragma unroll
        for (int ks = 0; ks < 4; ++ks) {
            bf16x8 a[4], bfrag;
            #pragma unroll
            for (int fm = 0; fm < 4; ++fm)
                a[fm] = *(const bf16x8*)(flc + (fm*16 + (lane&15))*136 + ks*32 + (lane>>4)*8);
            {   // b-frag: column gather from k-major f32 tile + pack to bf16
                int nl = wid*16 + (lane&15);
                int k0 = ks*32 + (lane>>4)*8;
                float v[8];
                #pragma unroll
                for (int d = 0; d < 8; ++d)
                    v[d] = wtc[(k0 + d)*64 + nl];
                unsigned int us[4] = { pack2bf(v[0],v[1]), pack2bf(v[2],v[3]),
                                       pack2bf(v[4],v[5]), pack2bf(v[6],v[7]) };
                bfrag = *(bf16x8*)us;
            }
            #pragma unroll
            for (int fm = 0; fm < 4; ++fm)
                acc[fm] = __builtin_amdgcn_mfma_f32_16x16x32_bf16(a[fm], bfrag, acc[fm], 0,0,0);
        }
        __builtin_amdgcn_s_setprio(0);
        if (t < 5) {
            unsigned short* fln = fl + (cur^1)*(64*136);
            #pragma unroll
            for (int s = 0; s < 4; ++s) {
                int idx = tid + s*256;
                int r = idx >> 4, c8 = idx & 15;
                unsigned int us32[4] = { pack2bf(rf[s][0].x, rf[s][0].y), pack2bf(rf[s][0].z, rf[s][0].w),
                                         pack2bf(rf[s][1].x, rf[s][1].y), pack2bf(rf[s][1].z, rf[s][1].w) };
                *(ushort8_t*)(fln + r*136 + c8*8) = *(ushort8_t*)us32;
            }
        }
        __syncthreads();
    }
    #pragma unroll
    for (int fm = 0; fm < 4; ++fm)
        #pragma unroll
        for (int q = 0; q < 4; ++q) {
            int row = m0 + fm*16 + (lane>>4)*4 + q;
            int col = n0 + wid*16 + (lane&15);
            float bias = (col < 768) ? b1[col] : 0.0f;   // fold b1 into A half
            AB[(size_t)row*1536 + col] = acc[fm][q] + bias;
        }
}

// ---------------- fused pair MLP (champion, verbatim): 16 waves, plain
// __syncthreads pipeline. phase A: 2x8 wave grid (64x48 tiles), dbuf h1 +
// dbuf w2 (gload_lds, swizzled); phase B: 4x4 grid (32x32), dbuf w3.
__launch_bounds__(1024, 1)
__global__ void fused_k(const float* __restrict__ AB,            // [256][1536] f32
                        const unsigned short* __restrict__ W2t,  // [384][768] bf16
                        const float* __restrict__ b2,            // [384]
                        const unsigned short* __restrict__ W3t,  // [128][384] bf16
                        const float* __restrict__ b3,            // [128]
                        float* __restrict__ out) {               // [32640][128] f32
    __shared__ alignas(1024) char smem[135168];
    unsigned short* h1b = (unsigned short*)(smem);            // 2 x [128][72]   (36,864 B)
    unsigned short* w2b = (unsigned short*)(smem + 36864);    // 2 x [384][64] swizzled (98,304 B)
    unsigned short* h2  = (unsigned short*)(smem);            // [128][392] phase B (reuse)
    unsigned short* w3b = (unsigned short*)(smem + 100352);   // 2 x [128][64] swizzled (32,768 B)

    int tid = threadIdx.x;
    int lane = tid & 63, wid = tid >> 6;   // 16 waves
    int wr = wid >> 3, wc = wid & 7;       // phase A: 2 x 8 wave grid
    int p0 = blockIdx.x * 128;

    int hr = tid >> 3;                     // 0..127
    int hc = (tid & 7) * 8;                // col chunk within 64
    int p = p0 + hr;
    float sdisc = sqrtf((float)(511*511 - 8*p));
    int i_me = (int)((511.0f - sdisc) * 0.5f);
    if (i_me < 0) i_me = 0; if (i_me > 254) i_me = 254;
    while (i_me < 255 && (i_me+1)*255 - (i_me+1)*i_me/2 <= p) ++i_me;
    while (i_me > 0 && i_me*255 - i_me*(i_me-1)/2 > p) --i_me;
    int j_me = i_me + 1 + (p - (i_me*255 - i_me*(i_me-1)/2));

    float4 ra[2], rb[2];

    // ---- prologue: h1(0) pack; w2(0) gloads; one barrier
    {
        const float4* pa = (const float4*)(AB + (size_t)i_me*1536 + hc);
        const float4* pb = (const float4*)(AB + (size_t)j_me*1536 + 768 + hc);
        ra[0] = pa[0]; ra[1] = pa[1]; rb[0] = pb[0]; rb[1] = pb[1];
        unsigned int us32[4];
        #pragma unroll
        for (int u = 0; u < 2; ++u) {
            us32[u*2+0] = pack2bf(fmaxf(ra[u].x + rb[u].x, 0.f), fmaxf(ra[u].y + rb[u].y, 0.f));
            us32[u*2+1] = pack2bf(fmaxf(ra[u].z + rb[u].z, 0.f), fmaxf(ra[u].w + rb[u].w, 0.f));
        }
        *(ushort8_t*)(h1b + hr*72 + hc) = *(ushort8_t*)us32;
    }
    #pragma unroll
    for (int s = 0; s < 3; ++s) {
        int chunk = wid*3 + s;                 // 48 chunks of 1024B
        int row = chunk*8 + (lane>>3);
        int cg = (lane&7) ^ (row&7);
        gload_lds16(W2t + (size_t)row*HID + cg*8, (char*)w2b + chunk*1024);
    }
    __syncthreads();

    f32x4 acc2[4][3] = {};
    for (int t = 0; t < 12; ++t) {
        int cur = t & 1;
        unsigned short* h1c = h1b + cur * (128*72);
        unsigned short* w2c = w2b + cur * (384*64);
        if (t < 11) {                          // issue next-step loads BEFORE compute
            int kk = (t+1) * 64;
            unsigned short* w2n = w2b + (cur^1) * (384*64);
            #pragma unroll
            for (int s = 0; s < 3; ++s) {
                int chunk = wid*3 + s;
                int row = chunk*8 + (lane>>3);
                int cg = (lane&7) ^ (row&7);
                gload_lds16(W2t + (size_t)row*HID + kk + cg*8, (char*)w2n + chunk*1024);
            }
            const float4* pa = (const float4*)(AB + (size_t)i_me*1536 + kk + hc);
            const float4* pb = (const float4*)(AB + (size_t)j_me*1536 + 768 + kk + hc);
            ra[0] = pa[0]; ra[1] = pa[1]; rb[0] = pb[0]; rb[1] = pb[1];
        }
        __builtin_amdgcn_s_setprio(1);
        #pragma unroll
        for (int ks = 0; ks < 2; ++ks) {
            bf16x8 a[4], bfr[3];
            #pragma unroll
            for (int fm = 0; fm < 4; ++fm)
                a[fm] = *(const bf16x8*)(h1c + (wr*64 + fm*16 + (lane&15))*72 + ks*32 + (lane>>4)*8);
            #pragma unroll
            for (int fn = 0; fn < 3; ++fn) {
                int n = wc*48 + fn*16 + (lane&15);
                int g = ks*4 + (lane>>4);
                bfr[fn] = *(const bf16x8*)(w2c + n*64 + ((g ^ (n&7)) * 8));
            }
            #pragma unroll
            for (int fm = 0; fm < 4; ++fm)
                #pragma unroll
                for (int fn = 0; fn < 3; ++fn)
                    acc2[fm][fn] = __builtin_amdgcn_mfma_f32_16x16x32_bf16(a[fm], bfr[fn], acc2[fm][fn], 0,0,0);
        }
        __builtin_amdgcn_s_setprio(0);
        if (t < 11) {                          // pack prefetched AB -> h1[next]
            unsigned short* h1n = h1b + (cur^1) * (128*72);
            unsigned int us32[4];
            #pragma unroll
            for (int u = 0; u < 2; ++u) {
                us32[u*2+0] = pack2bf(fmaxf(ra[u].x + rb[u].x, 0.f), fmaxf(ra[u].y + rb[u].y, 0.f));
                us32[u*2+1] = pack2bf(fmaxf(ra[u].z + rb[u].z, 0.f), fmaxf(ra[u].w + rb[u].w, 0.f));
            }
            *(ushort8_t*)(h1n + hr*72 + hc) = *(ushort8_t*)us32;
        }
        __syncthreads();
    }

    // ---- phase transition: h2 = relu(acc2 + b2) -> [128][392]; stage w3(0)
    #pragma unroll
    for (int fn = 0; fn < 3; ++fn) {
        int col = wc*48 + fn*16 + (lane&15);
        float bb = b2[col];
        #pragma unroll
        for (int fm = 0; fm < 4; ++fm)
            #pragma unroll
            for (int q = 0; q < 4; ++q) {
                int row = wr*64 + fm*16 + (lane>>4)*4 + q;
                h2[row*392 + col] = f2bf1(fmaxf(acc2[fm][fn][q] + bb, 0.f));
            }
    }
    {
        int chunk = wid;                       // 16 chunks, 1 per wave
        int row = chunk*8 + (lane>>3);
        int cg = (lane&7) ^ (row&7);
        gload_lds16(W3t + (size_t)row*384 + cg*8, (char*)w3b + chunk*1024);
    }
    __syncthreads();

    // ---- phase B: 4x4 wave grid, tile 32x32, dbuf w3
    int wrB = wid >> 2, wcB = wid & 3;
    f32x4 acc3[2][2] = {};
    for (int kt = 0; kt < 6; ++kt) {
        int cur = kt & 1;
        unsigned short* w3c = w3b + cur * (128*64);
        if (kt < 5) {
            unsigned short* w3n = w3b + (cur^1) * (128*64);
            int chunk = wid;
            int row = chunk*8 + (lane>>3);
            int cg = (lane&7) ^ (row&7);
            gload_lds16(W3t + (size_t)row*384 + (kt+1)*64 + cg*8, (char*)w3n + chunk*1024);
        }
        __builtin_amdgcn_s_setprio(1);
        #pragma unroll
        for (int ks = 0; ks < 2; ++ks) {
            bf16x8 a[2], bfr[2];
            #pragma unroll
            for (int fm = 0; fm < 2; ++fm)
                a[fm] = *(const bf16x8*)(h2 + (wrB*32 + fm*16 + (lane&15))*392 + kt*64 + ks*32 + (lane>>4)*8);
            #pragma unroll
            for (int fn = 0; fn < 2; ++fn) {
                int n = wcB*32 + fn*16 + (lane&15);
                int g = ks*4 + (lane>>4);
                bfr[fn] = *(const bf16x8*)(w3c + n*64 + ((g ^ (n&7)) * 8));
            }
            #pragma unroll
            for (int fm = 0; fm < 2; ++fm)
                #pragma unroll
                for (int fn = 0; fn < 2; ++fn)
                    acc3[fm][fn] = __builtin_amdgcn_mfma_f32_16x16x32_bf16(a[fm], bfr[fn], acc3[fm][fn], 0,0,0);
        }
        __builtin_amdgcn_s_setprio(0);
        __syncthreads();
    }
    #pragma unroll
    for (int fm = 0; fm < 2; ++fm)
        #pragma unroll
        for (int fn = 0; fn < 2; ++fn) {
            int col = wcB*32 + fn*16 + (lane&15);
            float bb = b3[col];
            #pragma unroll
            for (int q = 0; q < 4; ++q) {
                int row = p0 + wrB*32 + fm*16 + (lane>>4)*4 + q;
                out[(size_t)row*128 + col] = acc3[fm][fn][q] + bb;
            }
        }
}

extern "C" void kernel_launch(void* const* d_in, const int* in_sizes, int n_in,
                              void* d_out, int out_size, void* d_ws, size_t ws_size,
                              hipStream_t stream) {
    const float* feat = (const float*)d_in[0];  // [256][768]
    const float* W1   = (const float*)d_in[1];  // [1536][768]
    const float* b1   = (const float*)d_in[2];  // [768]
    const float* W2   = (const float*)d_in[3];  // [768][384]
    const float* b2   = (const float*)d_in[4];  // [384]
    const float* W3   = (const float*)d_in[5];  // [384][128]
    const float* b3   = (const float*)d_in[6];  // [128]
    float* out = (float*)d_out;

    char* ws = (char*)d_ws;
    unsigned short* W2t = (unsigned short*)(ws + 0);        // 384*768*2 = 589,824
    unsigned short* W3t = (unsigned short*)(ws + 589824);   // 128*384*2 =  98,304
    float*          AB  = (float*)        (ws + 688128);    // 256*1536*4 = 1,572,864

    prep_ab_k<<<432, 256, 0, stream>>>(feat, W1, b1, W2, W3, W2t, W3t, AB);
    fused_k<<<255, 1024, 0, stream>>>(AB, W2t, b2, W3t, b3, out);
}

// Round 16
// 44.221 us; speedup vs baseline: 1.2232x; 1.0691x over previous
//
#include <hip/hip_runtime.h>
#include <hip/hip_bf16.h>
#include <stdint.h>

#define HID 768

typedef short bf16x8 __attribute__((ext_vector_type(8)));
typedef unsigned short ushort8_t __attribute__((ext_vector_type(8)));
typedef float f32x4 __attribute__((ext_vector_type(4)));
typedef _Float16 f16x8 __attribute__((ext_vector_type(8)));

// packed f32x2 -> bf16x2 (compiler emits v_cvt_pk_bf16_f32)
__device__ __forceinline__ unsigned int pack2bf(float x, float y) {
    __hip_bfloat162 h = __float22bfloat162_rn(make_float2(x, y));
    return *reinterpret_cast<unsigned int*>(&h);
}

// async global->LDS, 16B per lane; lds dest = wave-uniform base + lane*16
__device__ __forceinline__ void gload_lds16(const void* g, void* l) {
    __builtin_amdgcn_global_load_lds(
        (const __attribute__((address_space(1))) unsigned int*)g,
        (__attribute__((address_space(3))) unsigned int*)l, 16, 0, 0);
}

// ---------------- combo: blocks 0..95 = AB gemm (W1 consumed untransposed,
//                  K-step 128 -> 6 barriered steps, f16 output); blocks
//                  96..431 = W2/W3 transpose+cast to f16. Plain barriers only.
__launch_bounds__(256, 2)
__global__ void prep_ab_k(const float* __restrict__ F,     // feat [256][768]
                          const float* __restrict__ W1,    // [1536][768] f32
                          const float* __restrict__ b1,    // [768]
                          const float* __restrict__ W2,    // [768][384]
                          const float* __restrict__ W3,    // [384][128]
                          _Float16* __restrict__ W2t,      // [384][768] f16
                          _Float16* __restrict__ W3t,      // [128][384] f16
                          _Float16* __restrict__ AB) {     // [256][1536] f16
    __shared__ alignas(1024) char smem[102400];
    int b = blockIdx.x;

    if (b >= 96) {
        // ---- transpose path: f32 [R][C] -> f16 [C][R]
        float (*t)[33] = (float(*)[33])smem;
        int b2 = b - 96;
        const float* in; _Float16* op; int R, C, bx, by;
        if (b2 < 288) { in = W2; op = W2t; R = 768; C = 384; bx = b2 % 12; by = b2 / 12; }
        else          { int b3i = b2 - 288; in = W3; op = W3t; R = 384; C = 128; bx = b3i % 4; by = b3i / 4; }
        int c0 = bx * 32, r0 = by * 32;
        int tx = threadIdx.x & 31, ty = threadIdx.x >> 5;   // 32 x 8
        #pragma unroll
        for (int k = 0; k < 4; ++k)
            t[ty + 8*k][tx] = in[(size_t)(r0 + ty + 8*k) * C + c0 + tx];
        __syncthreads();
        #pragma unroll
        for (int k = 0; k < 4; ++k)
            op[(size_t)(c0 + ty + 8*k) * R + r0 + tx] = (_Float16)t[tx][ty + 8*k];
        return;
    }

    // ---- gemm path: AB tile 64m x 64n, K=768 in 6 steps of 128
    unsigned short* fl = (unsigned short*)smem;             // 2 x [64][136] bf16 (34,816 B)
    float*          wt = (float*)(smem + 34816);            // 2 x [128][64] f32  (65,536 B)

    int tid = threadIdx.x;
    int lane = tid & 63, wid = tid >> 6;   // 4 waves
    int bx = b % 24, by = b / 24;
    int n0 = bx * 64, m0 = by * 64;
    const float* Wsrc = W1 + (n0 < 768 ? 0 : (size_t)768*768);
    int cb = (n0 < 768) ? n0 : n0 - 768;

    f32x4 acc[4] = {};
    float4 rf[4][2];

    #pragma unroll
    for (int s = 0; s < 8; ++s) {
        int chunk = wid*8 + s;
        int rk = chunk*4 + (lane>>4);
        int c16 = (lane&15)*4;
        gload_lds16(Wsrc + (size_t)rk*HID + cb + c16, (char*)wt + chunk*1024);
    }
    #pragma unroll
    for (int s = 0; s < 4; ++s) {
        int idx = tid + s*256;
        int r = idx >> 4, c8 = idx & 15;
        const float4* src = (const float4*)(F + (size_t)(m0 + r)*HID + c8*8);
        rf[s][0] = src[0]; rf[s][1] = src[1];
    }
    #pragma unroll
    for (int s = 0; s < 4; ++s) {
        int idx = tid + s*256;
        int r = idx >> 4, c8 = idx & 15;
        unsigned int us32[4] = { pack2bf(rf[s][0].x, rf[s][0].y), pack2bf(rf[s][0].z, rf[s][0].w),
                                 pack2bf(rf[s][1].x, rf[s][1].y), pack2bf(rf[s][1].z, rf[s][1].w) };
        *(ushort8_t*)(fl + r*136 + c8*8) = *(ushort8_t*)us32;
    }
    __syncthreads();

    for (int t = 0; t < 6; ++t) {
        int cur = t & 1;
        unsigned short* flc = fl + cur*(64*136);
        float* wtc = wt + cur*(128*64);
        if (t < 5) {
            int kk = (t+1) * 128;
            float* wtn = wt + (cur^1)*(128*64);
            #pragma unroll
            for (int s = 0; s < 8; ++s) {
                int chunk = wid*8 + s;
                int rk = chunk*4 + (lane>>4);
                int c16 = (lane&15)*4;
                gload_lds16(Wsrc + (size_t)(kk + rk)*HID + cb + c16, (char*)wtn + chunk*1024);
            }
            #pragma unroll
            for (int s = 0; s < 4; ++s) {
                int idx = tid + s*256;
                int r = idx >> 4, c8 = idx & 15;
                const float4* src = (const float4*)(F + (size_t)(m0 + r)*HID + kk + c8*8);
                rf[s][0] = src[0]; rf[s][1] = src[1];
            }
        }
        __builtin_amdgcn_s_setprio(1);
        #pragma unroll
        for (int ks = 0; ks < 4; ++ks) {
            bf16x8 a[4], bfrag;
            #pragma unroll
            for (int fm = 0; fm < 4; ++fm)
                a[fm] = *(const bf16x8*)(flc + (fm*16 + (lane&15))*136 + ks*32 + (lane>>4)*8);
            {   // b-frag: column gather from k-major f32 tile + pack to bf16
                int nl = wid*16 + (lane&15);
                int k0 = ks*32 + (lane>>4)*8;
                float v[8];
                #pragma unroll
                for (int d = 0; d < 8; ++d)
                    v[d] = wtc[(k0 + d)*64 + nl];
                unsigned int us[4] = { pack2bf(v[0],v[1]), pack2bf(v[2],v[3]),
                                       pack2bf(v[4],v[5]), pack2bf(v[6],v[7]) };
                bfrag = *(bf16x8*)us;
            }
            #pragma unroll
            for (int fm = 0; fm < 4; ++fm)
                acc[fm] = __builtin_amdgcn_mfma_f32_16x16x32_bf16(a[fm], bfrag, acc[fm], 0,0,0);
        }
        __builtin_amdgcn_s_setprio(0);
        if (t < 5) {
            unsigned short* fln = fl + (cur^1)*(64*136);
            #pragma unroll
            for (int s = 0; s < 4; ++s) {
                int idx = tid + s*256;
                int r = idx >> 4, c8 = idx & 15;
                unsigned int us32[4] = { pack2bf(rf[s][0].x, rf[s][0].y), pack2bf(rf[s][0].z, rf[s][0].w),
                                         pack2bf(rf[s][1].x, rf[s][1].y), pack2bf(rf[s][1].z, rf[s][1].w) };
                *(ushort8_t*)(fln + r*136 + c8*8) = *(ushort8_t*)us32;
            }
        }
        __syncthreads();
    }
    #pragma unroll
    for (int fm = 0; fm < 4; ++fm)
        #pragma unroll
        for (int q = 0; q < 4; ++q) {
            int row = m0 + fm*16 + (lane>>4)*4 + q;
            int col = n0 + wid*16 + (lane&15);
            float bias = (col < 768) ? b1[col] : 0.0f;   // fold b1 into A half
            AB[(size_t)row*1536 + col] = (_Float16)(acc[fm][q] + bias);
        }
}

// ---------------- fused pair MLP: champion structure, f16 datapath -------------
// 16 waves, plain __syncthreads pipeline. phase A: 2x8 wave grid (64x48 tiles),
// dbuf h1 + dbuf w2 (gload_lds, swizzled); phase B: 4x4 grid (32x32), dbuf w3.
__launch_bounds__(1024, 1)
__global__ void fused_k(const _Float16* __restrict__ AB,         // [256][1536] f16
                        const _Float16* __restrict__ W2t,        // [384][768] f16
                        const float* __restrict__ b2,            // [384]
                        const _Float16* __restrict__ W3t,        // [128][384] f16
                        const float* __restrict__ b3,            // [128]
                        float* __restrict__ out) {               // [32640][128] f32
    __shared__ alignas(1024) char smem[135168];
    _Float16* h1b = (_Float16*)(smem);            // 2 x [128][72]   (36,864 B)
    _Float16* w2b = (_Float16*)(smem + 36864);    // 2 x [384][64] swizzled (98,304 B)
    _Float16* h2  = (_Float16*)(smem);            // [128][392] phase B (reuse)
    _Float16* w3b = (_Float16*)(smem + 100352);   // 2 x [128][64] swizzled (32,768 B)

    int tid = threadIdx.x;
    int lane = tid & 63, wid = tid >> 6;   // 16 waves
    int wr = wid >> 3, wc = wid & 7;       // phase A: 2 x 8 wave grid
    int p0 = blockIdx.x * 128;

    int hr = tid >> 3;                     // 0..127
    int hc = (tid & 7) * 8;                // col chunk within 64
    int p = p0 + hr;
    float sdisc = sqrtf((float)(511*511 - 8*p));
    int i_me = (int)((511.0f - sdisc) * 0.5f);
    if (i_me < 0) i_me = 0; if (i_me > 254) i_me = 254;
    while (i_me < 255 && (i_me+1)*255 - (i_me+1)*i_me/2 <= p) ++i_me;
    while (i_me > 0 && i_me*255 - i_me*(i_me-1)/2 > p) --i_me;
    int j_me = i_me + 1 + (p - (i_me*255 - i_me*(i_me-1)/2));

    f16x8 va, vb;
    const f16x8 fz = {};

    // ---- prologue: h1(0) pack; w2(0) gloads; one barrier
    {
        va = *(const f16x8*)(AB + (size_t)i_me*1536 + hc);
        vb = *(const f16x8*)(AB + (size_t)j_me*1536 + 768 + hc);
        *(f16x8*)(h1b + hr*72 + hc) = __builtin_elementwise_max(va + vb, fz);
    }
    #pragma unroll
    for (int s = 0; s < 3; ++s) {
        int chunk = wid*3 + s;                 // 48 chunks of 1024B
        int row = chunk*8 + (lane>>3);
        int cg = (lane&7) ^ (row&7);
        gload_lds16(W2t + (size_t)row*HID + cg*8, (char*)w2b + chunk*1024);
    }
    __syncthreads();

    f32x4 acc2[4][3] = {};
    for (int t = 0; t < 12; ++t) {
        int cur = t & 1;
        _Float16* h1c = h1b + cur * (128*72);
        _Float16* w2c = w2b + cur * (384*64);
        if (t < 11) {                          // issue next-step loads BEFORE compute
            int kk = (t+1) * 64;
            _Float16* w2n = w2b + (cur^1) * (384*64);
            #pragma unroll
            for (int s = 0; s < 3; ++s) {
                int chunk = wid*3 + s;
                int row = chunk*8 + (lane>>3);
                int cg = (lane&7) ^ (row&7);
                gload_lds16(W2t + (size_t)row*HID + kk + cg*8, (char*)w2n + chunk*1024);
            }
            va = *(const f16x8*)(AB + (size_t)i_me*1536 + kk + hc);
            vb = *(const f16x8*)(AB + (size_t)j_me*1536 + 768 + kk + hc);
        }
        __builtin_amdgcn_s_setprio(1);
        #pragma unroll
        for (int ks = 0; ks < 2; ++ks) {
            f16x8 a[4], bfr[3];
            #pragma unroll
            for (int fm = 0; fm < 4; ++fm)
                a[fm] = *(const f16x8*)(h1c + (wr*64 + fm*16 + (lane&15))*72 + ks*32 + (lane>>4)*8);
            #pragma unroll
            for (int fn = 0; fn < 3; ++fn) {
                int n = wc*48 + fn*16 + (lane&15);
                int g = ks*4 + (lane>>4);
                bfr[fn] = *(const f16x8*)(w2c + n*64 + ((g ^ (n&7)) * 8));
            }
            #pragma unroll
            for (int fm = 0; fm < 4; ++fm)
                #pragma unroll
                for (int fn = 0; fn < 3; ++fn)
                    acc2[fm][fn] = __builtin_amdgcn_mfma_f32_16x16x32_f16(a[fm], bfr[fn], acc2[fm][fn], 0,0,0);
        }
        __builtin_amdgcn_s_setprio(0);
        if (t < 11) {                          // pack prefetched AB -> h1[next]
            _Float16* h1n = h1b + (cur^1) * (128*72);
            *(f16x8*)(h1n + hr*72 + hc) = __builtin_elementwise_max(va + vb, fz);
        }
        __syncthreads();
    }

    // ---- phase transition: h2 = relu(acc2 + b2) -> [128][392]; stage w3(0)
    #pragma unroll
    for (int fn = 0; fn < 3; ++fn) {
        int col = wc*48 + fn*16 + (lane&15);
        float bb = b2[col];
        #pragma unroll
        for (int fm = 0; fm < 4; ++fm)
            #pragma unroll
            for (int q = 0; q < 4; ++q) {
                int row = wr*64 + fm*16 + (lane>>4)*4 + q;
                h2[row*392 + col] = (_Float16)fmaxf(acc2[fm][fn][q] + bb, 0.f);
            }
    }
    {
        int chunk = wid;                       // 16 chunks, 1 per wave
        int row = chunk*8 + (lane>>3);
        int cg = (lane&7) ^ (row&7);
        gload_lds16(W3t + (size_t)row*384 + cg*8, (char*)w3b + chunk*1024);
    }
    __syncthreads();

    // ---- phase B: 4x4 wave grid, tile 32x32, dbuf w3
    int wrB = wid >> 2, wcB = wid & 3;
    f32x4 acc3[2][2] = {};
    for (int kt = 0; kt < 6; ++kt) {
        int cur = kt & 1;
        _Float16* w3c = w3b + cur * (128*64);
        if (kt < 5) {
            _Float16* w3n = w3b + (cur^1) * (128*64);
            int chunk = wid;
            int row = chunk*8 + (lane>>3);
            int cg = (lane&7) ^ (row&7);
            gload_lds16(W3t + (size_t)row*384 + (kt+1)*64 + cg*8, (char*)w3n + chunk*1024);
        }
        __builtin_amdgcn_s_setprio(1);
        #pragma unroll
        for (int ks = 0; ks < 2; ++ks) {
            f16x8 a[2], bfr[2];
            #pragma unroll
            for (int fm = 0; fm < 2; ++fm)
                a[fm] = *(const f16x8*)(h2 + (wrB*32 + fm*16 + (lane&15))*392 + kt*64 + ks*32 + (lane>>4)*8);
            #pragma unroll
            for (int fn = 0; fn < 2; ++fn) {
                int n = wcB*32 + fn*16 + (lane&15);
                int g = ks*4 + (lane>>4);
                bfr[fn] = *(const f16x8*)(w3c + n*64 + ((g ^ (n&7)) * 8));
            }
            #pragma unroll
            for (int fm = 0; fm < 2; ++fm)
                #pragma unroll
                for (int fn = 0; fn < 2; ++fn)
                    acc3[fm][fn] = __builtin_amdgcn_mfma_f32_16x16x32_f16(a[fm], bfr[fn], acc3[fm][fn], 0,0,0);
        }
        __builtin_amdgcn_s_setprio(0);
        __syncthreads();
    }
    #pragma unroll
    for (int fm = 0; fm < 2; ++fm)
        #pragma unroll
        for (int fn = 0; fn < 2; ++fn) {
            int col = wcB*32 + fn*16 + (lane&15);
            float bb = b3[col];
            #pragma unroll
            for (int q = 0; q < 4; ++q) {
                int row = p0 + wrB*32 + fm*16 + (lane>>4)*4 + q;
                out[(size_t)row*128 + col] = acc3[fm][fn][q] + bb;
            }
        }
}

extern "C" void kernel_launch(void* const* d_in, const int* in_sizes, int n_in,
                              void* d_out, int out_size, void* d_ws, size_t ws_size,
                              hipStream_t stream) {
    const float* feat = (const float*)d_in[0];  // [256][768]
    const float* W1   = (const float*)d_in[1];  // [1536][768]
    const float* b1   = (const float*)d_in[2];  // [768]
    const float* W2   = (const float*)d_in[3];  // [768][384]
    const float* b2   = (const float*)d_in[4];  // [384]
    const float* W3   = (const float*)d_in[5];  // [384][128]
    const float* b3   = (const float*)d_in[6];  // [128]
    float* out = (float*)d_out;

    char* ws = (char*)d_ws;
    _Float16* W2t = (_Float16*)(ws + 0);        // 384*768*2 = 589,824
    _Float16* W3t = (_Float16*)(ws + 589824);   // 128*384*2 =  98,304
    _Float16* AB  = (_Float16*)(ws + 688128);   // 256*1536*2 = 786,432

    prep_ab_k<<<432, 256, 0, stream>>>(feat, W1, b1, W2, W3, W2t, W3t, AB);
    fused_k<<<255, 1024, 0, stream>>>(AB, W2t, b2, W3t, b3, out);
}

// Round 17
// 43.236 us; speedup vs baseline: 1.2511x; 1.0228x over previous
//
#include <hip/hip_runtime.h>
#include <hip/hip_bf16.h>
#include <stdint.h>

#define HID 768

typedef short bf16x8 __attribute__((ext_vector_type(8)));
typedef unsigned short ushort8_t __attribute__((ext_vector_type(8)));
typedef float f32x4 __attribute__((ext_vector_type(4)));
typedef _Float16 f16x8 __attribute__((ext_vector_type(8)));

// packed f32x2 -> bf16x2 (compiler emits v_cvt_pk_bf16_f32)
__device__ __forceinline__ unsigned int pack2bf(float x, float y) {
    __hip_bfloat162 h = __float22bfloat162_rn(make_float2(x, y));
    return *reinterpret_cast<unsigned int*>(&h);
}

// async global->LDS, 16B per lane; lds dest = wave-uniform base + lane*16
__device__ __forceinline__ void gload_lds16(const void* g, void* l) {
    __builtin_amdgcn_global_load_lds(
        (const __attribute__((address_space(1))) unsigned int*)g,
        (__attribute__((address_space(3))) unsigned int*)l, 16, 0, 0);
}

// ---------------- combo: blocks 0..95 = AB gemm (W1 gathered straight from L2,
//                  no LDS staging for W1 — zero intra-block reuse); blocks
//                  96..431 = W2/W3 transpose+cast to f16. Plain barriers only.
__launch_bounds__(256, 2)
__global__ void prep_ab_k(const float* __restrict__ F,     // feat [256][768]
                          const float* __restrict__ W1,    // [1536][768] f32
                          const float* __restrict__ b1,    // [768]
                          const float* __restrict__ W2,    // [768][384]
                          const float* __restrict__ W3,    // [384][128]
                          _Float16* __restrict__ W2t,      // [384][768] f16
                          _Float16* __restrict__ W3t,      // [128][384] f16
                          _Float16* __restrict__ AB) {     // [256][1536] f16
    __shared__ alignas(1024) char smem[36864];
    int b = blockIdx.x;

    if (b >= 96) {
        // ---- transpose path: f32 [R][C] -> f16 [C][R]
        float (*t)[33] = (float(*)[33])smem;
        int b2 = b - 96;
        const float* in; _Float16* op; int R, C, bx, by;
        if (b2 < 288) { in = W2; op = W2t; R = 768; C = 384; bx = b2 % 12; by = b2 / 12; }
        else          { int b3i = b2 - 288; in = W3; op = W3t; R = 384; C = 128; bx = b3i % 4; by = b3i / 4; }
        int c0 = bx * 32, r0 = by * 32;
        int tx = threadIdx.x & 31, ty = threadIdx.x >> 5;   // 32 x 8
        #pragma unroll
        for (int k = 0; k < 4; ++k)
            t[ty + 8*k][tx] = in[(size_t)(r0 + ty + 8*k) * C + c0 + tx];
        __syncthreads();
        #pragma unroll
        for (int k = 0; k < 4; ++k)
            op[(size_t)(c0 + ty + 8*k) * R + r0 + tx] = (_Float16)t[tx][ty + 8*k];
        return;
    }

    // ---- gemm path: AB tile 64m x 64n, K=768 in 6 steps of 128
    unsigned short* fl = (unsigned short*)smem;             // 2 x [64][136] bf16 (34,816 B)

    int tid = threadIdx.x;
    int lane = tid & 63, wid = tid >> 6;   // 4 waves
    int bx = b % 24, by = b / 24;
    int n0 = bx * 64, m0 = by * 64;
    const float* Wsrc = W1 + (n0 < 768 ? 0 : (size_t)768*768);
    int cb = (n0 < 768) ? n0 : n0 - 768;
    int nl = wid*16 + (lane&15);           // my n column within tile

    f32x4 acc[4] = {};
    float4 rf[4][2];

    // prologue: F tile [64 m][128 k] f32 -> regs -> bf16 LDS
    #pragma unroll
    for (int s = 0; s < 4; ++s) {
        int idx = tid + s*256;
        int r = idx >> 4, c8 = idx & 15;
        const float4* src = (const float4*)(F + (size_t)(m0 + r)*HID + c8*8);
        rf[s][0] = src[0]; rf[s][1] = src[1];
    }
    #pragma unroll
    for (int s = 0; s < 4; ++s) {
        int idx = tid + s*256;
        int r = idx >> 4, c8 = idx & 15;
        unsigned int us32[4] = { pack2bf(rf[s][0].x, rf[s][0].y), pack2bf(rf[s][0].z, rf[s][0].w),
                                 pack2bf(rf[s][1].x, rf[s][1].y), pack2bf(rf[s][1].z, rf[s][1].w) };
        *(ushort8_t*)(fl + r*136 + c8*8) = *(ushort8_t*)us32;
    }
    __syncthreads();

    for (int t = 0; t < 6; ++t) {
        int cur = t & 1;
        unsigned short* flc = fl + cur*(64*136);
        int kt = t * 128;
        // gather W1 b-frag columns for this step straight from global (L2-hot):
        // lanes 0-15 read 64B-contiguous per (ks,d); each line touched once/block.
        float v[4][8];
        #pragma unroll
        for (int ks = 0; ks < 4; ++ks) {
            int k0 = kt + ks*32 + (lane>>4)*8;
            #pragma unroll
            for (int d = 0; d < 8; ++d)
                v[ks][d] = Wsrc[(size_t)(k0 + d)*HID + cb + nl];
        }
        if (t < 5) {                        // F prefetch for t+1
            int kk = (t+1) * 128;
            #pragma unroll
            for (int s = 0; s < 4; ++s) {
                int idx = tid + s*256;
                int r = idx >> 4, c8 = idx & 15;
                const float4* src = (const float4*)(F + (size_t)(m0 + r)*HID + kk + c8*8);
                rf[s][0] = src[0]; rf[s][1] = src[1];
            }
        }
        __builtin_amdgcn_s_setprio(1);
        #pragma unroll
        for (int ks = 0; ks < 4; ++ks) {
            bf16x8 a[4], bfrag;
            #pragma unroll
            for (int fm = 0; fm < 4; ++fm)
                a[fm] = *(const bf16x8*)(flc + (fm*16 + (lane&15))*136 + ks*32 + (lane>>4)*8);
            {
                unsigned int us[4] = { pack2bf(v[ks][0],v[ks][1]), pack2bf(v[ks][2],v[ks][3]),
                                       pack2bf(v[ks][4],v[ks][5]), pack2bf(v[ks][6],v[ks][7]) };
                bfrag = *(bf16x8*)us;
            }
            #pragma unroll
            for (int fm = 0; fm < 4; ++fm)
                acc[fm] = __builtin_amdgcn_mfma_f32_16x16x32_bf16(a[fm], bfrag, acc[fm], 0,0,0);
        }
        __builtin_amdgcn_s_setprio(0);
        if (t < 5) {
            unsigned short* fln = fl + (cur^1)*(64*136);
            #pragma unroll
            for (int s = 0; s < 4; ++s) {
                int idx = tid + s*256;
                int r = idx >> 4, c8 = idx & 15;
                unsigned int us32[4] = { pack2bf(rf[s][0].x, rf[s][0].y), pack2bf(rf[s][0].z, rf[s][0].w),
                                         pack2bf(rf[s][1].x, rf[s][1].y), pack2bf(rf[s][1].z, rf[s][1].w) };
                *(ushort8_t*)(fln + r*136 + c8*8) = *(ushort8_t*)us32;
            }
        }
        __syncthreads();
    }
    #pragma unroll
    for (int fm = 0; fm < 4; ++fm)
        #pragma unroll
        for (int q = 0; q < 4; ++q) {
            int row = m0 + fm*16 + (lane>>4)*4 + q;
            int col = n0 + wid*16 + (lane&15);
            float bias = (col < 768) ? b1[col] : 0.0f;   // fold b1 into A half
            AB[(size_t)row*1536 + col] = (_Float16)(acc[fm][q] + bias);
        }
}

// ---------------- fused pair MLP: champion structure, f16 datapath (verbatim) --
// 16 waves, plain __syncthreads pipeline. phase A: 2x8 wave grid (64x48 tiles),
// dbuf h1 + dbuf w2 (gload_lds, swizzled); phase B: 4x4 grid (32x32), dbuf w3.
__launch_bounds__(1024, 1)
__global__ void fused_k(const _Float16* __restrict__ AB,         // [256][1536] f16
                        const _Float16* __restrict__ W2t,        // [384][768] f16
                        const float* __restrict__ b2,            // [384]
                        const _Float16* __restrict__ W3t,        // [128][384] f16
                        const float* __restrict__ b3,            // [128]
                        float* __restrict__ out) {               // [32640][128] f32
    __shared__ alignas(1024) char smem[135168];
    _Float16* h1b = (_Float16*)(smem);            // 2 x [128][72]   (36,864 B)
    _Float16* w2b = (_Float16*)(smem + 36864);    // 2 x [384][64] swizzled (98,304 B)
    _Float16* h2  = (_Float16*)(smem);            // [128][392] phase B (reuse)
    _Float16* w3b = (_Float16*)(smem + 100352);   // 2 x [128][64] swizzled (32,768 B)

    int tid = threadIdx.x;
    int lane = tid & 63, wid = tid >> 6;   // 16 waves
    int wr = wid >> 3, wc = wid & 7;       // phase A: 2 x 8 wave grid
    int p0 = blockIdx.x * 128;

    int hr = tid >> 3;                     // 0..127
    int hc = (tid & 7) * 8;                // col chunk within 64
    int p = p0 + hr;
    float sdisc = sqrtf((float)(511*511 - 8*p));
    int i_me = (int)((511.0f - sdisc) * 0.5f);
    if (i_me < 0) i_me = 0; if (i_me > 254) i_me = 254;
    while (i_me < 255 && (i_me+1)*255 - (i_me+1)*i_me/2 <= p) ++i_me;
    while (i_me > 0 && i_me*255 - i_me*(i_me-1)/2 > p) --i_me;
    int j_me = i_me + 1 + (p - (i_me*255 - i_me*(i_me-1)/2));

    f16x8 va, vb;
    const f16x8 fz = {};

    // ---- prologue: h1(0) pack; w2(0) gloads; one barrier
    {
        va = *(const f16x8*)(AB + (size_t)i_me*1536 + hc);
        vb = *(const f16x8*)(AB + (size_t)j_me*1536 + 768 + hc);
        *(f16x8*)(h1b + hr*72 + hc) = __builtin_elementwise_max(va + vb, fz);
    }
    #pragma unroll
    for (int s = 0; s < 3; ++s) {
        int chunk = wid*3 + s;                 // 48 chunks of 1024B
        int row = chunk*8 + (lane>>3);
        int cg = (lane&7) ^ (row&7);
        gload_lds16(W2t + (size_t)row*HID + cg*8, (char*)w2b + chunk*1024);
    }
    __syncthreads();

    f32x4 acc2[4][3] = {};
    for (int t = 0; t < 12; ++t) {
        int cur = t & 1;
        _Float16* h1c = h1b + cur * (128*72);
        _Float16* w2c = w2b + cur * (384*64);
        if (t < 11) {                          // issue next-step loads BEFORE compute
            int kk = (t+1) * 64;
            _Float16* w2n = w2b + (cur^1) * (384*64);
            #pragma unroll
            for (int s = 0; s < 3; ++s) {
                int chunk = wid*3 + s;
                int row = chunk*8 + (lane>>3);
                int cg = (lane&7) ^ (row&7);
                gload_lds16(W2t + (size_t)row*HID + kk + cg*8, (char*)w2n + chunk*1024);
            }
            va = *(const f16x8*)(AB + (size_t)i_me*1536 + kk + hc);
            vb = *(const f16x8*)(AB + (size_t)j_me*1536 + 768 + kk + hc);
        }
        __builtin_amdgcn_s_setprio(1);
        #pragma unroll
        for (int ks = 0; ks < 2; ++ks) {
            f16x8 a[4], bfr[3];
            #pragma unroll
            for (int fm = 0; fm < 4; ++fm)
                a[fm] = *(const f16x8*)(h1c + (wr*64 + fm*16 + (lane&15))*72 + ks*32 + (lane>>4)*8);
            #pragma unroll
            for (int fn = 0; fn < 3; ++fn) {
                int n = wc*48 + fn*16 + (lane&15);
                int g = ks*4 + (lane>>4);
                bfr[fn] = *(const f16x8*)(w2c + n*64 + ((g ^ (n&7)) * 8));
            }
            #pragma unroll
            for (int fm = 0; fm < 4; ++fm)
                #pragma unroll
                for (int fn = 0; fn < 3; ++fn)
                    acc2[fm][fn] = __builtin_amdgcn_mfma_f32_16x16x32_f16(a[fm], bfr[fn], acc2[fm][fn], 0,0,0);
        }
        __builtin_amdgcn_s_setprio(0);
        if (t < 11) {                          // pack prefetched AB -> h1[next]
            _Float16* h1n = h1b + (cur^1) * (128*72);
            *(f16x8*)(h1n + hr*72 + hc) = __builtin_elementwise_max(va + vb, fz);
        }
        __syncthreads();
    }

    // ---- phase transition: h2 = relu(acc2 + b2) -> [128][392]; stage w3(0)
    #pragma unroll
    for (int fn = 0; fn < 3; ++fn) {
        int col = wc*48 + fn*16 + (lane&15);
        float bb = b2[col];
        #pragma unroll
        for (int fm = 0; fm < 4; ++fm)
            #pragma unroll
            for (int q = 0; q < 4; ++q) {
                int row = wr*64 + fm*16 + (lane>>4)*4 + q;
                h2[row*392 + col] = (_Float16)fmaxf(acc2[fm][fn][q] + bb, 0.f);
            }
    }
    {
        int chunk = wid;                       // 16 chunks, 1 per wave
        int row = chunk*8 + (lane>>3);
        int cg = (lane&7) ^ (row&7);
        gload_lds16(W3t + (size_t)row*384 + cg*8, (char*)w3b + chunk*1024);
    }
    __syncthreads();

    // ---- phase B: 4x4 wave grid, tile 32x32, dbuf w3
    int wrB = wid >> 2, wcB = wid & 3;
    f32x4 acc3[2][2] = {};
    for (int kt = 0; kt < 6; ++kt) {
        int cur = kt & 1;
        _Float16* w3c = w3b + cur * (128*64);
        if (kt < 5) {
            _Float16* w3n = w3b + (cur^1) * (128*64);
            int chunk = wid;
            int row = chunk*8 + (lane>>3);
            int cg = (lane&7) ^ (row&7);
            gload_lds16(W3t + (size_t)row*384 + (kt+1)*64 + cg*8, (char*)w3n + chunk*1024);
        }
        __builtin_amdgcn_s_setprio(1);
        #pragma unroll
        for (int ks = 0; ks < 2; ++ks) {
            f16x8 a[2], bfr[2];
            #pragma unroll
            for (int fm = 0; fm < 2; ++fm)
                a[fm] = *(const f16x8*)(h2 + (wrB*32 + fm*16 + (lane&15))*392 + kt*64 + ks*32 + (lane>>4)*8);
            #pragma unroll
            for (int fn = 0; fn < 2; ++fn) {
                int n = wcB*32 + fn*16 + (lane&15);
                int g = ks*4 + (lane>>4);
                bfr[fn] = *(const f16x8*)(w3c + n*64 + ((g ^ (n&7)) * 8));
            }
            #pragma unroll
            for (int fm = 0; fm < 2; ++fm)
                #pragma unroll
                for (int fn = 0; fn < 2; ++fn)
                    acc3[fm][fn] = __builtin_amdgcn_mfma_f32_16x16x32_f16(a[fm], bfr[fn], acc3[fm][fn], 0,0,0);
        }
        __builtin_amdgcn_s_setprio(0);
        __syncthreads();
    }
    #pragma unroll
    for (int fm = 0; fm < 2; ++fm)
        #pragma unroll
        for (int fn = 0; fn < 2; ++fn) {
            int col = wcB*32 + fn*16 + (lane&15);
            float bb = b3[col];
            #pragma unroll
            for (int q = 0; q < 4; ++q) {
                int row = p0 + wrB*32 + fm*16 + (lane>>4)*4 + q;
                out[(size_t)row*128 + col] = acc3[fm][fn][q] + bb;
            }
        }
}

extern "C" void kernel_launch(void* const* d_in, const int* in_sizes, int n_in,
                              void* d_out, int out_size, void* d_ws, size_t ws_size,
                              hipStream_t stream) {
    const float* feat = (const float*)d_in[0];  // [256][768]
    const float* W1   = (const float*)d_in[1];  // [1536][768]
    const float* b1   = (const float*)d_in[2];  // [768]
    const float* W2   = (const float*)d_in[3];  // [768][384]
    const float* b2   = (const float*)d_in[4];  // [384]
    const float* W3   = (const float*)d_in[5];  // [384][128]
    const float* b3   = (const float*)d_in[6];  // [128]
    float* out = (float*)d_out;

    char* ws = (char*)d_ws;
    _Float16* W2t = (_Float16*)(ws + 0);        // 384*768*2 = 589,824
    _Float16* W3t = (_Float16*)(ws + 589824);   // 128*384*2 =  98,304
    _Float16* AB  = (_Float16*)(ws + 688128);   // 256*1536*2 = 786,432

    prep_ab_k<<<432, 256, 0, stream>>>(feat, W1, b1, W2, W3, W2t, W3t, AB);
    fused_k<<<255, 1024, 0, stream>>>(AB, W2t, b2, W3t, b3, out);
}